// Round 15
// baseline (108.337 us; speedup 1.0000x reference)
//
#include <hip/hip_runtime.h>
#include <hip/hip_bf16.h>

#define TT 2048
#define NB 16
#define FD 128
#define ALPHA 0.2f

typedef __attribute__((ext_vector_type(8))) short short8;
typedef __attribute__((ext_vector_type(4))) float f32x4;
typedef __attribute__((ext_vector_type(16))) float f32x16;

static __device__ __forceinline__ unsigned short f2bf(float f) {
    unsigned u = __float_as_uint(f);
    u += 0x7FFF + ((u >> 16) & 1);          // round-to-nearest-even
    return (unsigned short)(u >> 16);
}
static __device__ __forceinline__ unsigned short bfbits(float f) {
    return __builtin_bit_cast(unsigned short, __float2bfloat16(f));  // HW RNE cvt
}

// Kernel P: arithmetic bitmask pack, 256 MB -> 8 MB, pure stream.
__global__ __launch_bounds__(256) void k_pack(const int* __restrict__ adj,
                                              unsigned char* __restrict__ bm)
{
    const int tid = threadIdx.x;
    const int w = tid >> 6, l = tid & 63;
    const int row = blockIdx.x * 4 + w;          // 32768 rows
    const int* ap = adj + (size_t)row * TT + l * 4;
    unsigned char* op = bm + (size_t)row * 256;

    #pragma unroll
    for (int rd = 0; rd < 8; ++rd) {             // 256 j per wave-round
        int4 q = *reinterpret_cast<const int4*>(ap + rd * 256);
        unsigned n =  min((unsigned)q.x, 1u)
                   | (min((unsigned)q.y, 1u) << 1)
                   | (min((unsigned)q.z, 1u) << 2)
                   | (min((unsigned)q.w, 1u) << 3);
        unsigned pn = (unsigned)__shfl_xor((int)n, 1);
        if ((l & 1) == 0)
            op[rd * 32 + (l >> 1)] = (unsigned char)(n | (pn << 4));
    }
}

// Kernel 0: WT[f][k] = bf16(W[k][f])  (128x128, tiny)
__global__ __launch_bounds__(256) void k_wt(const float* __restrict__ W,
                                            unsigned short* __restrict__ WT)
{
    int fid = blockIdx.x * 256 + threadIdx.x;   // 4096 float4s
    int k = fid >> 5;
    int f = (fid & 31) << 2;
    float4 w4 = *reinterpret_cast<const float4*>(W + k * FD + f);
    WT[(f + 0) * FD + k] = f2bf(w4.x);
    WT[(f + 1) * FD + k] = f2bf(w4.y);
    WT[(f + 2) * FD + k] = f2bf(w4.z);
    WT[(f + 3) * FD + k] = f2bf(w4.w);
}

// Kernel 1: h = x@W, n-split for occupancy: 512-thread blocks, 8 waves;
// wave (wr, ng) computes rows wr*16.. and n-frags ng*4..ng*4+3 (2x waves/CU
// vs the 4-wave version -> hides the HBM x-load latency). s1/s2 partials
// combined across sibling waves via LDS. hF written fragment-linear for
// mfma_f32_32x32x16_bf16 as before.
__global__ __launch_bounds__(512) void k_h(const float* __restrict__ x,
                                           const unsigned short* __restrict__ WT,
                                           const float* __restrict__ a,
                                           unsigned short* __restrict__ hF,
                                           float* __restrict__ s1,
                                           float* __restrict__ s2)
{
    __shared__ unsigned short hs[128][72];   // 18.4 KB
    __shared__ float ps1[2][64], ps2[2][64]; // n-half partials, 1 KB

    const int tid = threadIdx.x;
    const int b  = blockIdx.x >> 5;
    const int t0 = (blockIdx.x & 31) << 6;
    const int wv = tid >> 6, l = tid & 63, g = l >> 4, r15 = l & 15;
    const int wr = wv >> 1, ng = wv & 1;     // row-group, n-half

    const float* xrow = x + ((size_t)(b * TT + t0 + wr * 16 + r15)) * FD;

    f32x4 acc[4] = {};

    #pragma unroll
    for (int m = 0; m < 4; ++m) {
        const int koff = m * 32 + g * 8;
        float4 xa = *reinterpret_cast<const float4*>(xrow + koff);
        float4 xb = *reinterpret_cast<const float4*>(xrow + koff + 4);
        short8 af;
        af[0] = (short)f2bf(xa.x); af[1] = (short)f2bf(xa.y);
        af[2] = (short)f2bf(xa.z); af[3] = (short)f2bf(xa.w);
        af[4] = (short)f2bf(xb.x); af[5] = (short)f2bf(xb.y);
        af[6] = (short)f2bf(xb.z); af[7] = (short)f2bf(xb.w);
        #pragma unroll
        for (int nn = 0; nn < 4; ++nn) {
            const int n = ng * 4 + nn;
            short8 bfr = *reinterpret_cast<const short8*>(WT + (n * 16 + r15) * FD + koff);
            acc[nn] = __builtin_amdgcn_mfma_f32_16x16x32_bf16(af, bfr, acc[nn], 0, 0, 0);
        }
    }

    // s1/s2 partials over this wave's 4 n-frags
    float p1[4] = {0.f, 0.f, 0.f, 0.f}, p2[4] = {0.f, 0.f, 0.f, 0.f};
    #pragma unroll
    for (int nn = 0; nn < 4; ++nn) {
        const int n = ng * 4 + nn;
        float a1v = a[n * 16 + r15];
        float a2v = a[FD + n * 16 + r15];
        #pragma unroll
        for (int r = 0; r < 4; ++r) {
            p1[r] += acc[nn][r] * a1v;
            p2[r] += acc[nn][r] * a2v;
        }
    }
    #pragma unroll
    for (int r = 0; r < 4; ++r) {
        #pragma unroll
        for (int off = 8; off >= 1; off >>= 1) {
            p1[r] += __shfl_xor(p1[r], off);
            p2[r] += __shfl_xor(p2[r], off);
        }
    }
    if (r15 == 0) {
        #pragma unroll
        for (int r = 0; r < 4; ++r) {
            ps1[ng][wr * 16 + g * 4 + r] = p1[r];
            ps2[ng][wr * 16 + g * 4 + r] = p2[r];
        }
    }

    // stage h tile (bf16) transposed: hs[f][t_local]
    #pragma unroll
    for (int nn = 0; nn < 4; ++nn)
        #pragma unroll
        for (int r = 0; r < 4; ++r)
            hs[(ng * 4 + nn) * 16 + r15][wr * 16 + g * 4 + r] = f2bf(acc[nn][r]);
    __syncthreads();

    if (tid < 64) {                          // combine n-halves, write s1/s2
        s1[b * TT + t0 + tid] = ps1[0][tid] + ps1[1][tid];
        s2[b * TT + t0 + tid] = ps2[0][tid] + ps2[1][tid];
    }

    // write fragment-linear hF: 16 frags x 64 lanes over 512 threads = 2 iters
    #pragma unroll
    for (int it = 0; it < 2; ++it) {
        int idx = it * 512 + tid;            // 0..1023
        int lp = idx & 63;                   // consumer lane
        int frag = idx >> 6;                 // 0..15
        int n32 = frag & 3, tl = frag >> 2;  // local j16 tile
        int fsrc = n32 * 32 + (lp & 31);
        int tsrc = tl * 16 + (lp >> 5) * 8;
        short8 v = *reinterpret_cast<const short8*>(&hs[fsrc][tsrc]);
        *reinterpret_cast<short8*>(
            hF + (((size_t)(b * 128 + (t0 >> 4) + tl)) * 4 + n32) * 512 + lp * 8) = v;
    }
}

// Kernel 2: fused mask+softmax+PV, barrier-free main loop.
// Clean vm-queue discipline: bm hoisted to 4 prologue uint4s (registers),
// s2 staged to LDS (lgkm queue) -> the main-loop vm queue carries ONLY
// B-fragment loads, so the depth-2 ring (3 slots) keeps 2 steps in flight
// under in-order vmcnt retirement (covers L2 ~200cy).
__global__ __launch_bounds__(256, 3) void k_att(const unsigned char* __restrict__ bm,
                                                const unsigned short* __restrict__ hF,
                                                const float* __restrict__ s1,
                                                const float* __restrict__ s2,
                                                float* __restrict__ out)
{
    __shared__ float s2b[TT];                         // 8 KB
    __shared__ __align__(16) float red[2][32][132];   // 33.8 KB
    __shared__ float dsum[4][32];

    const int tid = threadIdx.x;
    // bijective XCD swizzle: 1024 blocks = 8 XCDs x 128 contiguous
    const int wg = (blockIdx.x & 7) * 128 + (blockIdx.x >> 3);
    const int b  = wg >> 6;
    const int i0 = (wg & 63) << 5;
    const int w = tid >> 6, l = tid & 63;
    const int il = l & 31, h = l >> 5;        // A row, k-half
    const int hsh = h * 8;

    // stage s2 row into LDS (coalesced)
    {
        float4 v0 = *reinterpret_cast<const float4*>(s2 + b * TT + tid * 8);
        float4 v1 = *reinterpret_cast<const float4*>(s2 + b * TT + tid * 8 + 4);
        *reinterpret_cast<float4*>(&s2b[tid * 8])     = v0;
        *reinterpret_cast<float4*>(&s2b[tid * 8 + 4]) = v1;
    }
    const float s1v = s1[b * TT + i0 + il];

    const int jbeg = w * (TT / 4);
    const unsigned char* bmrow = bm + ((size_t)(b * TT + i0 + il)) * 256 + w * 64;
    const unsigned short* hfp = hF + ((size_t)(b * 128 + (jbeg >> 4))) * 4 * 512 + l * 8;

    // hoist this thread's whole bitmask quarter into registers (16 VGPR)
    uint4 bq[4];
    bq[0] = *reinterpret_cast<const uint4*>(bmrow);
    bq[1] = *reinterpret_cast<const uint4*>(bmrow + 16);
    bq[2] = *reinterpret_cast<const uint4*>(bmrow + 32);
    bq[3] = *reinterpret_cast<const uint4*>(bmrow + 48);

    __syncthreads();                          // s2b ready
    const float* s2w = &s2b[jbeg + h * 8];

    f32x16 acc[4] = {};
    float rsum = 0.f;

    short8 bb[3][4];                          // depth-2 B ring (3 slots)
    #pragma unroll
    for (int p = 0; p < 2; ++p)
        #pragma unroll
        for (int n = 0; n < 4; ++n)
            bb[p][n] = *reinterpret_cast<const short8*>(hfp + (size_t)(p * 4 + n) * 512);

    #pragma unroll
    for (int t = 0; t < 32; ++t) {            // 16 j per step; indices static
        const int slot = t % 3;
        if (t < 30) {                         // prefetch 2 steps ahead
            const int ns = (t + 2) % 3;
            #pragma unroll
            for (int n = 0; n < 4; ++n)
                bb[ns][n] = *reinterpret_cast<const short8*>(
                    hfp + (size_t)((t + 2) * 4 + n) * 512);
        }
        const int wi = t >> 3;                // static
        const uint4 bqw = bq[wi];
        const int ci = (t >> 1) & 3;
        const unsigned wsel = ci == 0 ? bqw.x : ci == 1 ? bqw.y : ci == 2 ? bqw.z : bqw.w;
        const unsigned bits = (wsel >> ((t & 1) * 16 + hsh)) & 0xffu;

        float4 sa = *reinterpret_cast<const float4*>(&s2w[t * 16]);
        float4 sb = *reinterpret_cast<const float4*>(&s2w[t * 16 + 4]);
        float csf[8] = {sa.x, sa.y, sa.z, sa.w, sb.x, sb.y, sb.z, sb.w};
        float pv[8];
        #pragma unroll
        for (int e = 0; e < 8; ++e) {
            float s = s1v + csf[e];
            s = fmaxf(s, ALPHA * s);                     // leaky_relu
            float p = ((int)(bits << (31 - e)) < 0) ? __expf(s) : 0.f;
            rsum += p;                                   // denom (unrounded)
            pv[e] = p;
        }
        short8 af;
        #pragma unroll
        for (int e = 0; e < 8; ++e)
            af[e] = (short)bfbits(pv[e]);                // HW RNE cvt
        #pragma unroll
        for (int n = 0; n < 4; ++n)
            acc[n] = __builtin_amdgcn_mfma_f32_32x32x16_bf16(af, bb[slot][n],
                                                             acc[n], 0, 0, 0);
    }

    // quarter row-sums: combine the two k-halves, store per-wave partials
    rsum += __shfl_xor(rsum, 32);
    if (l < 32) dsum[w][l] = rsum;

    // two-step LDS reduction of the 4 wave-partial accumulators
    if (w < 2) {
        #pragma unroll
        for (int n = 0; n < 4; ++n)
            #pragma unroll
            for (int r = 0; r < 16; ++r) {
                int irow = (r & 3) + 8 * (r >> 2) + 4 * h;
                red[w][irow][n * 32 + il] = acc[n][r];
            }
    }
    __syncthreads();
    if (w >= 2) {
        #pragma unroll
        for (int n = 0; n < 4; ++n)
            #pragma unroll
            for (int r = 0; r < 16; ++r) {
                int irow = (r & 3) + 8 * (r >> 2) + 4 * h;
                red[w - 2][irow][n * 32 + il] += acc[n][r];
            }
    }
    __syncthreads();

    // epilogue: 32 rows x 128 cols = 1024 float4 over 256 threads
    #pragma unroll
    for (int it = 0; it < 4; ++it) {
        int e = it * 256 + tid;
        int row = e >> 5;
        int c4 = (e & 31) << 2;
        float4 v0 = *reinterpret_cast<const float4*>(&red[0][row][c4]);
        float4 v1 = *reinterpret_cast<const float4*>(&red[1][row][c4]);
        float dn = dsum[0][row] + dsum[1][row] + dsum[2][row] + dsum[3][row];
        float ri = 1.0f / dn;
        float4 o;
        o.x = (v0.x + v1.x) * ri;
        o.y = (v0.y + v1.y) * ri;
        o.z = (v0.z + v1.z) * ri;
        o.w = (v0.w + v1.w) * ri;
        *reinterpret_cast<float4*>(out + ((size_t)(b * TT + i0 + row)) * FD + c4) = o;
    }
}

extern "C" void kernel_launch(void* const* d_in, const int* in_sizes, int n_in,
                              void* d_out, int out_size, void* d_ws, size_t ws_size,
                              hipStream_t stream)
{
    const float* x  = (const float*)d_in[0];
    const int* adj  = (const int*)d_in[1];
    const float* W  = (const float*)d_in[2];
    const float* a  = (const float*)d_in[3];
    float* out = (float*)d_out;

    unsigned short* hF = (unsigned short*)d_ws;                       // 8 MB bf16 (fragment-linear)
    float* s1 = (float*)((char*)d_ws + (size_t)NB * FD * TT * 2);
    float* s2 = s1 + NB * TT;
    unsigned short* WT = (unsigned short*)(s2 + NB * TT);             // 32 KB
    unsigned char* bm = (unsigned char*)(WT + FD * FD);               // 8 MB bitmask

    k_wt  <<<16, 256, 0, stream>>>(W, WT);
    k_h   <<<NB * (TT / 64), 512, 0, stream>>>(x, WT, a, hF, s1, s2);
    k_pack<<<NB * TT / 4, 256, 0, stream>>>(adj, bm);
    k_att <<<NB * (TT / 32), 256, 0, stream>>>(bm, hF, s1, s2, out);
}